// Round 1
// baseline (107.766 us; speedup 1.0000x reference)
//
#include <hip/hip_runtime.h>

#define NB 4096
#define MM 128
#define NN 96
#define LL 20

// One block (128 threads = 2 waves) per batch.
// Thread (rg = tid>>3, cg = tid&7) owns H[rg*8 .. rg*8+7][cg*12 .. cg*12+11]
// in registers (96 VGPRs). Loop: u = H*yx (reduce over cg via shfl),
// u -= y, w = H^T*u (reduce over rg via LDS scatter), elementwise update by
// per-column owner lanes (tid<96).
__global__ __launch_bounds__(128)
void pg_kernel(const float* __restrict__ x_ini,
               const float* __restrict__ y,
               const float* __restrict__ H,
               const float* __restrict__ xt,
               const float* __restrict__ grad_ss,
               const float* __restrict__ extra_ss,
               const float* __restrict__ gamma1,
               float* __restrict__ out)
{
    const int b   = blockIdx.x;
    const int tid = threadIdx.x;
    const int cg  = tid & 7;    // column group: cols cg*12 .. +11
    const int rg  = tid >> 3;   // row group:    rows rg*8  .. +7

    __shared__ float lds_wp[16][97];  // 97 stride -> <=2-way bank aliasing (free)
    __shared__ float lds_yx[96];
    __shared__ float pgs[LL], pes[LL], pgm[LL];
    __shared__ float lsum[2];

    if (tid < LL) {
        pgs[tid] = grad_ss[tid];
        pes[tid] = extra_ss[tid];
        pgm[tid] = gamma1[tid];
    }

    // ---- load own H tile into registers (read H from HBM exactly once) ----
    float h[8][12];
    const float* Hb = H + (size_t)b * (MM * NN) + (size_t)(rg * 8) * NN + cg * 12;
    #pragma unroll
    for (int i = 0; i < 8; ++i) {
        #pragma unroll
        for (int k = 0; k < 3; ++k) {
            float4 v = *reinterpret_cast<const float4*>(Hb + i * NN + 4 * k);
            h[i][4*k+0] = v.x; h[i][4*k+1] = v.y;
            h[i][4*k+2] = v.z; h[i][4*k+3] = v.w;
        }
    }

    // ---- own rows of y ----
    float yr[8];
    {
        const float* yb = y + (size_t)b * MM + rg * 8;
        float4 v0 = *reinterpret_cast<const float4*>(yb);
        float4 v1 = *reinterpret_cast<const float4*>(yb + 4);
        yr[0]=v0.x; yr[1]=v0.y; yr[2]=v0.z; yr[3]=v0.w;
        yr[4]=v1.x; yr[5]=v1.y; yr[6]=v1.z; yr[7]=v1.w;
    }

    // ---- init y_x / x for the column this lane owns ----
    float yx_c = 0.f, x_c = 0.f;
    if (tid < NN) {
        yx_c = x_ini[(size_t)b * NN + tid];
        x_c  = yx_c;
        lds_yx[tid] = yx_c;
    }
    __syncthreads();

    // replicated y_x for this thread's 12 columns
    float yx[12];
    #pragma unroll
    for (int k = 0; k < 3; ++k) {
        float4 v = *reinterpret_cast<const float4*>(&lds_yx[cg * 12 + 4 * k]);
        yx[4*k+0]=v.x; yx[4*k+1]=v.y; yx[4*k+2]=v.z; yx[4*k+3]=v.w;
    }

    for (int t = 0; t < LL; ++t) {
        // ---- matvec1: u = H * yx (partial over own 12 cols) ----
        float u[8];
        #pragma unroll
        for (int i = 0; i < 8; ++i) {
            float s = 0.f;
            #pragma unroll
            for (int j = 0; j < 12; ++j) s = fmaf(h[i][j], yx[j], s);
            u[i] = s;
        }
        // reduce across the 8 column groups (adjacent lanes)
        #pragma unroll
        for (int m = 1; m <= 4; m <<= 1) {
            #pragma unroll
            for (int i = 0; i < 8; ++i) u[i] += __shfl_xor(u[i], m, 64);
        }
        // u = H*yx - y   (so that H^T u = HTH*yx - HTy)
        #pragma unroll
        for (int i = 0; i < 8; ++i) u[i] -= yr[i];

        // ---- matvec2 partials: wp_j = sum_i h[i][j] * u[i], scatter to LDS ----
        #pragma unroll
        for (int j = 0; j < 12; ++j) {
            float s = 0.f;
            #pragma unroll
            for (int i = 0; i < 8; ++i) s = fmaf(h[i][j], u[i], s);
            lds_wp[rg][cg * 12 + j] = s;
        }
        __syncthreads();

        const float gs = pgs[t], es = pes[t], gm = pgm[t];
        if (tid < NN) {
            float w = 0.f;
            #pragma unroll
            for (int r = 0; r < 16; ++r) w += lds_wp[r][tid];
            // x_buff = y_x - gs * 2 * (H^T(H yx - y))
            float xb  = fmaf(-2.0f * gs, w, yx_c);
            // nearest of {-2,0,2}
            float cen = 2.0f * fminf(fmaxf(rintf(xb * 0.5f), -1.0f), 1.0f);
            float z   = gm * (xb - cen);
            float e   = __expf(-z);
            float ply = fmaf(2.0f, __builtin_amdgcn_rcpf(1.0f + e), -1.0f);
            yx_c = fmaf(es, ply - x_c, ply);   // y_x_new = ply + es*(ply - x)
            x_c  = ply;                        // x = ply
            lds_yx[tid] = yx_c;
        }
        __syncthreads();

        if (t + 1 < LL) {
            #pragma unroll
            for (int k = 0; k < 3; ++k) {
                float4 v = *reinterpret_cast<const float4*>(&lds_yx[cg * 12 + 4 * k]);
                yx[4*k+0]=v.x; yx[4*k+1]=v.y; yx[4*k+2]=v.z; yx[4*k+3]=v.w;
            }
        }
    }

    // ---- epilogue: write x, accumulate loss ----
    float part = 0.f;
    if (tid < NN) {
        out[(size_t)b * NN + tid] = x_c;
        float d = x_c - xt[(size_t)b * NN + tid];
        part = d * d;
    }
    #pragma unroll
    for (int m = 1; m < 64; m <<= 1) part += __shfl_xor(part, m, 64);
    if ((tid & 63) == 0) lsum[tid >> 6] = part;
    __syncthreads();
    if (tid == 0) atomicAdd(out + (size_t)NB * NN, lsum[0] + lsum[1]);
}

extern "C" void kernel_launch(void* const* d_in, const int* in_sizes, int n_in,
                              void* d_out, int out_size, void* d_ws, size_t ws_size,
                              hipStream_t stream) {
    const float* x_ini   = (const float*)d_in[0];
    const float* y       = (const float*)d_in[1];
    const float* H       = (const float*)d_in[2];
    const float* xt      = (const float*)d_in[3];
    const float* grad_ss = (const float*)d_in[4];
    const float* extra_ss= (const float*)d_in[5];
    const float* gamma1  = (const float*)d_in[6];
    float* out = (float*)d_out;

    // zero the loss accumulator slot each call (graph-capture safe)
    hipMemsetAsync(out + (size_t)NB * NN, 0, sizeof(float), stream);

    pg_kernel<<<NB, 128, 0, stream>>>(x_ini, y, H, xt,
                                      grad_ss, extra_ss, gamma1, out);
}